// Round 18
// baseline (57.778 us; speedup 1.0000x reference)
//
#include <hip/hip_runtime.h>
#include <math.h>

typedef unsigned short ushort_t;
typedef unsigned int uint_t;
typedef __attribute__((ext_vector_type(8))) short short8v;       // 8 bf16 = 4 VGPR
typedef __attribute__((ext_vector_type(4))) float float4v;       // MFMA accum
typedef __attribute__((ext_vector_type(4))) unsigned short ushort4v; // 8B load

static __device__ __forceinline__ ushort_t f2bf(float f) {
    union { float f; uint_t u; } v; v.f = f;
    uint_t r = (v.u + 0x7FFFu + ((v.u >> 16) & 1u)) >> 16;       // RNE
    return (ushort_t)r;
}
static __device__ __forceinline__ float bf2f(ushort_t u) {
    union { uint_t u; float f; } v; v.u = ((uint_t)u) << 16;
    return v.f;
}

// ---------------------------------------------------------------------------
// K1: blocks 0..1023: conv1+pool -> conv2+pool (MFMA) -> p2g bf16 in
// QUAD-MAJOR layout (k' = quad*64 + oc): conv2's per-lane stores become
// 2B-contiguous across lanes (coalesced). Blocks 1024..1219: convert fc1w
// fp32 -> bf16 into wb with the SAME k-permutation so fc1 dot products are
// unchanged.
// ---------------------------------------------------------------------------
__global__ __launch_bounds__(256) void k_conv(
    const float* __restrict__ x,
    const float* __restrict__ c1w, const float* __restrict__ c1b,
    const float* __restrict__ c2w, const float* __restrict__ c2b,
    const float* __restrict__ fc1w, ushort_t* __restrict__ wb,
    ushort_t* __restrict__ p2g)
{
    const int t = threadIdx.x;
    if (blockIdx.x >= 1024) {                                 // fused cvtw (permuted)
        const int i   = (blockIdx.x - 1024)*256 + t;          // 0..50175 = 128*392
        const int row = i / 392;
        const int kp0 = (i - row*392) * 8;                    // k' base, 8-aligned
        const int quad = kp0 >> 6;
        const int oc0  = kp0 & 63;
        const float* src = fc1w + (size_t)row*3136 + quad;    // k = oc*49 + quad
        short8v pk;
        #pragma unroll
        for (int e = 0; e < 8; ++e) pk[e] = (short)f2bf(src[(size_t)(oc0+e)*49]);
        *(short8v*)(wb + (size_t)row*3136 + kp0) = pk;
        return;
    }

    __shared__ __align__(16) ushort_t p1cl[8192];            // 16 KB, 4 ic-planes
    __shared__ __align__(16) float img[900];                 // 30x30 padded

    const int b = blockIdx.x;
    const int lane = t & 63, wv = t >> 6;

    for (int i = t; i < 4096; i += 256) ((uint_t*)p1cl)[i] = 0u;
    for (int i = t; i < 900; i += 256) img[i] = 0.f;
    __syncthreads();
    const float* xi = x + (size_t)b * 784;
    for (int i = t; i < 784; i += 256)
        img[(i/28 + 1)*30 + (i%28 + 1)] = xi[i];
    __syncthreads();

    // ---- conv1 (1->32) + ReLU + maxpool2 -> p1cl (bf16, plane = wv) ----
    {
        const int ocb1 = wv*8;
        float wk[8][9], bv[8];
        #pragma unroll
        for (int o = 0; o < 8; ++o) {
            bv[o] = c1b[ocb1 + o];
            #pragma unroll
            for (int k = 0; k < 9; ++k) wk[o][k] = c1w[(ocb1 + o)*9 + k];
        }
        #pragma unroll
        for (int ch = 0; ch < 4; ++ch) {
            int pos = ch*64 + lane;
            const bool act = pos < 196;
            if (!act) pos = 195;
            const int qy = pos / 14, qx = pos % 14;
            const float* ib = img + (2*qy)*30 + 2*qx;
            float v[4][4];
            #pragma unroll
            for (int rr = 0; rr < 4; ++rr) {
                const float2 a = *(const float2*)(ib + rr*30);
                const float2 c = *(const float2*)(ib + rr*30 + 2);
                v[rr][0]=a.x; v[rr][1]=a.y; v[rr][2]=c.x; v[rr][3]=c.y;
            }
            short8v pk;
            #pragma unroll
            for (int o = 0; o < 8; ++o) {
                float m = 0.f;                                // relu(max)==max(0,max)
                #pragma unroll
                for (int dy = 0; dy < 2; ++dy)
                #pragma unroll
                for (int dx = 0; dx < 2; ++dx) {
                    float acc = bv[o];
                    #pragma unroll
                    for (int ky = 0; ky < 3; ++ky)
                    #pragma unroll
                    for (int kx = 0; kx < 3; ++kx)
                        acc = fmaf(v[dy+ky][dx+kx], wk[o][ky*3+kx], acc);
                    m = fmaxf(m, acc);
                }
                pk[o] = (short)f2bf(m);
            }
            if (act) *(short8v*)&p1cl[wv*2048 + ((qy+1)*16 + (qx+1))*8] = pk;
        }
    }
    __syncthreads();

    // ---- conv2 (32->64) + ReLU + maxpool2 via MFMA -> p2g (bf16, quad-major) ----
    {
        const int ocb = wv*16;
        const int col = lane & 15, g = lane >> 4;
        const int oc  = ocb + col;
        short8v bfr[9];
        #pragma unroll
        for (int j = 0; j < 8; ++j) {
            const float* wp = c2w + ((size_t)oc*32 + g*8 + j)*9;
            #pragma unroll
            for (int s = 0; s < 9; ++s) bfr[s][j] = (short)f2bf(wp[s]);
        }
        const float bv = c2b[oc];
        ushort_t* po = p2g + (size_t)b*3136;
        #pragma unroll 1
        for (int mt = 0; mt < 13; ++mt) {
            int row = mt*16 + col; if (row > 195) row = 195;
            const int q  = row >> 2;
            const int py = q / 7, px = q - py*7;
            const int y0 = 2*py + ((row>>1)&1), x0 = 2*px + (row&1);
            const ushort_t* ap = &p1cl[g*2048 + (y0*16 + x0)*8];
            float4v c0 = {bv, bv, bv, bv};
            float4v c1 = {0.f, 0.f, 0.f, 0.f};
            c0 = __builtin_amdgcn_mfma_f32_16x16x32_bf16(*(const short8v*)(ap +   0), bfr[0], c0, 0, 0, 0);
            c1 = __builtin_amdgcn_mfma_f32_16x16x32_bf16(*(const short8v*)(ap +   8), bfr[1], c1, 0, 0, 0);
            c0 = __builtin_amdgcn_mfma_f32_16x16x32_bf16(*(const short8v*)(ap +  16), bfr[2], c0, 0, 0, 0);
            c1 = __builtin_amdgcn_mfma_f32_16x16x32_bf16(*(const short8v*)(ap + 128), bfr[3], c1, 0, 0, 0);
            c0 = __builtin_amdgcn_mfma_f32_16x16x32_bf16(*(const short8v*)(ap + 136), bfr[4], c0, 0, 0, 0);
            c1 = __builtin_amdgcn_mfma_f32_16x16x32_bf16(*(const short8v*)(ap + 144), bfr[5], c1, 0, 0, 0);
            c0 = __builtin_amdgcn_mfma_f32_16x16x32_bf16(*(const short8v*)(ap + 256), bfr[6], c0, 0, 0, 0);
            c1 = __builtin_amdgcn_mfma_f32_16x16x32_bf16(*(const short8v*)(ap + 264), bfr[7], c1, 0, 0, 0);
            c0 = __builtin_amdgcn_mfma_f32_16x16x32_bf16(*(const short8v*)(ap + 272), bfr[8], c0, 0, 0, 0);
            const int quad = mt*4 + g;
            if (quad < 49) {
                const float m0 = fmaxf(fmaxf(c0[0]+c1[0], c0[1]+c1[1]),
                                       fmaxf(c0[2]+c1[2], c0[3]+c1[3]));
                po[quad*64 + oc] = f2bf(fmaxf(m0, 0.f));      // coalesced store
            }
        }
    }
}

// ---------------------------------------------------------------------------
// K2: fc1 as bf16 MFMA GEMM (unchanged — both operands share the permuted
// k-order). C[img16][oc16] per block; grid (64 imgT, 8 ocT). K = 98 chunks
// of 32 split 25/25/24/24 across 4 waves; 2-stage pipelined.
// ---------------------------------------------------------------------------
__global__ __launch_bounds__(256) void k_fc1(
    const ushort_t* __restrict__ p2g, const ushort_t* __restrict__ wb,
    const float* __restrict__ fc1b, float* __restrict__ h1g)
{
    __shared__ float cred[4][16][16];
    const int t = threadIdx.x, lane = t & 63, wv = t >> 6;
    const int imgT = blockIdx.x, ocT = blockIdx.y;
    const int sel = lane & 15, koff = (lane >> 4) * 8;
    const ushort_t* arow = p2g + (size_t)(imgT*16 + sel)*3136;
    const ushort_t* brow = wb  + (size_t)(ocT*16 + sel)*3136;
    const int n    = (wv < 2) ? 25 : 24;                      // 25+25+24+24 = 98
    const int kbeg = wv*24 + (wv < 2 ? wv : 2);
    float4v c = {0.f, 0.f, 0.f, 0.f};
    int k0 = kbeg*32 + koff;
    short8v a0 = *(const short8v*)(arow + k0);
    short8v b0 = *(const short8v*)(brow + k0);
    for (int kk = 1; kk < n; ++kk) {
        const int k1 = (kbeg + kk)*32 + koff;
        const short8v a1 = *(const short8v*)(arow + k1);
        const short8v b1 = *(const short8v*)(brow + k1);
        c = __builtin_amdgcn_mfma_f32_16x16x32_bf16(a0, b0, c, 0, 0, 0);
        a0 = a1; b0 = b1;
    }
    c = __builtin_amdgcn_mfma_f32_16x16x32_bf16(a0, b0, c, 0, 0, 0);
    #pragma unroll
    for (int r = 0; r < 4; ++r) cred[wv][(lane>>4)*4 + r][sel] = c[r];
    __syncthreads();
    const int m = t >> 4, nn = t & 15;
    const float s = cred[0][m][nn] + cred[1][m][nn] + cred[2][m][nn] + cred[3][m][nn]
                  + fc1b[ocT*16 + nn];
    h1g[(size_t)(imgT*16 + m)*128 + ocT*16 + nn] = fmaxf(s, 0.f);
}

// ---------------------------------------------------------------------------
// K3: tail (verified). 64-thread blocks, 4 samples each, grid 256.
// fc2+ReLU, fc3+ReLU, 4-qubit circuit via shfl, fc4, log_softmax.
// ---------------------------------------------------------------------------
__global__ __launch_bounds__(64) void k_head(
    const float* __restrict__ h1,
    const float* __restrict__ fc2w, const float* __restrict__ fc2b,
    const float* __restrict__ fc3w, const float* __restrict__ fc3b,
    const float* __restrict__ qw,
    const float* __restrict__ fc4w, const float* __restrict__ fc4b,
    float* __restrict__ out)
{
    __shared__ float h1s[4][132];
    __shared__ float h2s[4][68];
    __shared__ float fs[4][16];
    __shared__ float zs[4][12];
    const int t = threadIdx.x;                   // 0..63, one wave
    const int r = t >> 4, l = t & 15;            // sample-in-block, lane-in-sample
    const int b0 = blockIdx.x * 4;
    for (int i = t; i < 4*128; i += 64) h1s[i>>7][i&127] = h1[(size_t)b0*128 + i];
    __syncthreads();

    // fc2: each thread computes outputs o0..o0+3 of its sample
    const int o0 = l*4;
    float a0 = fc2b[o0+0], a1 = fc2b[o0+1], a2 = fc2b[o0+2], a3 = fc2b[o0+3];
    #pragma unroll 4
    for (int k4 = 0; k4 < 32; ++k4) {
        const float4 h  = *(const float4*)&h1s[r][k4*4];
        const float4 w0 = *(const float4*)&fc2w[(o0+0)*128 + k4*4];
        const float4 w1 = *(const float4*)&fc2w[(o0+1)*128 + k4*4];
        const float4 w2 = *(const float4*)&fc2w[(o0+2)*128 + k4*4];
        const float4 w3 = *(const float4*)&fc2w[(o0+3)*128 + k4*4];
        a0 = fmaf(h.x,w0.x,fmaf(h.y,w0.y,fmaf(h.z,w0.z,fmaf(h.w,w0.w,a0))));
        a1 = fmaf(h.x,w1.x,fmaf(h.y,w1.y,fmaf(h.z,w1.z,fmaf(h.w,w1.w,a1))));
        a2 = fmaf(h.x,w2.x,fmaf(h.y,w2.y,fmaf(h.z,w2.z,fmaf(h.w,w2.w,a2))));
        a3 = fmaf(h.x,w3.x,fmaf(h.y,w3.y,fmaf(h.z,w3.z,fmaf(h.w,w3.w,a3))));
    }
    {
        float4 v = make_float4(fmaxf(a0,0.f), fmaxf(a1,0.f), fmaxf(a2,0.f), fmaxf(a3,0.f));
        *(float4*)&h2s[r][o0] = v;
    }
    __syncthreads();

    // fc3: thread computes feat[l]
    float facc = fc3b[l];
    #pragma unroll 4
    for (int k4 = 0; k4 < 16; ++k4) {
        const float4 h  = *(const float4*)&h2s[r][k4*4];
        const float4 wv = *(const float4*)&fc3w[l*64 + k4*4];
        facc = fmaf(h.x,wv.x,fmaf(h.y,wv.y,fmaf(h.z,wv.z,fmaf(h.w,wv.w,facc))));
    }
    const float feat = fmaxf(facc, 0.f);
    fs[r][l] = feat;

    // ---- quantum circuit: amplitude per lane (bit of qubit q is 3-q) ----
    float nrm2 = feat*feat;
    nrm2 += __shfl_xor(nrm2, 1);
    nrm2 += __shfl_xor(nrm2, 2);
    nrm2 += __shfl_xor(nrm2, 4);
    nrm2 += __shfl_xor(nrm2, 8);
    const float nrm = fmaxf(sqrtf(nrm2), 1e-12f);
    float re = feat / nrm, im = 0.f;
    #pragma unroll
    for (int layer = 0; layer < 2; ++layer) {
        #pragma unroll
        for (int q = 0; q < 4; ++q) {
            const float phi = qw[(layer*4 + q)*3 + 0];
            const float th  = qw[(layer*4 + q)*3 + 1];
            const float om  = qw[(layer*4 + q)*3 + 2];
            float st, ct; sincosf(0.5f*th, &st, &ct);
            float sa, ca; sincosf(0.5f*(phi + om), &sa, &ca);   // ep = ca - i sa
            float sb, cb; sincosf(0.5f*(phi - om), &sb, &cb);   // em = cb + i sb
            const int pbit = 3 - q;
            const int bit  = (l >> pbit) & 1;
            const float pre = __shfl_xor(re, 1 << pbit);
            const float pim = __shfl_xor(im, 1 << pbit);
            const float sel = bit ? 1.f : -1.f;
            const float coR = ca*ct;
            const float coI = sel*sa*ct;
            const float cpR = sel*cb*st;
            const float cpI = -sb*st;
            const float nr = coR*re - coI*im + cpR*pre - cpI*pim;
            const float ni = coR*im + coI*re + cpR*pim + cpI*pre;
            re = nr; im = ni;
        }
        #pragma unroll
        for (int q = 0; q < 3; ++q) {          // CNOT control=q, target=q+1
            const int cbit = 3 - q, tbit = 2 - q;
            const float sre = __shfl_xor(re, 1 << tbit);
            const float sim = __shfl_xor(im, 1 << tbit);
            if ((l >> cbit) & 1) { re = sre; im = sim; }
        }
    }
    const float pr = fmaf(re, re, im*im);
    float qo[4];
    #pragma unroll
    for (int q = 0; q < 4; ++q) {
        float v = ((l >> (3-q)) & 1) ? -pr : pr;
        v += __shfl_xor(v, 1);
        v += __shfl_xor(v, 2);
        v += __shfl_xor(v, 4);
        v += __shfl_xor(v, 8);
        qo[q] = v;
    }
    __syncthreads();

    // fc4 + log_softmax (10 lanes per sample active)
    if (l < 10) {
        float z = fc4b[l];
        #pragma unroll
        for (int j = 0; j < 16; ++j) z = fmaf(fs[r][j], fc4w[l*20 + j], z);
        #pragma unroll
        for (int j = 0; j < 4; ++j)  z = fmaf(qo[j], fc4w[l*20 + 16 + j], z);
        zs[r][l] = z;
        float mx = zs[r][0];
        #pragma unroll
        for (int j = 1; j < 10; ++j) mx = fmaxf(mx, zs[r][j]);
        float se = 0.f;
        #pragma unroll
        for (int j = 0; j < 10; ++j) se += expf(zs[r][j] - mx);
        out[(size_t)(b0 + r)*10 + l] = z - mx - logf(se);
    }
}

// ---------------------------------------------------------------------------
// Serial per-sample head (verified round 3+), used by fallback monolith.
// ---------------------------------------------------------------------------
static __device__ __forceinline__ void circuit_head(
    const float* feat_in, const float* __restrict__ qw,
    const float* __restrict__ fc4w, const float* __restrict__ fc4b,
    float* __restrict__ outp)
{
    float feat[16];
    #pragma unroll
    for (int j = 0; j < 16; ++j) feat[j] = feat_in[j];
    float nrm2 = 0.f;
    #pragma unroll
    for (int j = 0; j < 16; ++j) nrm2 += feat[j]*feat[j];
    const float inv = 1.f / fmaxf(sqrtf(nrm2), 1e-12f);
    float ar[16], ai[16];
    #pragma unroll
    for (int j = 0; j < 16; ++j) { ar[j] = feat[j]*inv; ai[j] = 0.f; }
    #pragma unroll
    for (int layer = 0; layer < 2; ++layer) {
        #pragma unroll
        for (int q = 0; q < 4; ++q) {
            const float phi = qw[(layer*4 + q)*3 + 0];
            const float th  = qw[(layer*4 + q)*3 + 1];
            const float om  = qw[(layer*4 + q)*3 + 2];
            float st, ct; sincosf(0.5f*th, &st, &ct);
            float sa, ca; sincosf(0.5f*(phi + om), &sa, &ca);
            float sb, cb; sincosf(0.5f*(phi - om), &sb, &cb);
            const float U00r =  ca*ct, U00i = -sa*ct;
            const float U01r = -cb*st, U01i = -sb*st;
            const float U10r =  cb*st, U10i = -sb*st;
            const float U11r =  ca*ct, U11i =  sa*ct;
            const int stride = 1 << (3 - q);
            #pragma unroll
            for (int i0 = 0; i0 < 16; ++i0) {
                if (i0 & stride) continue;
                const int i1 = i0 | stride;
                const float r0 = ar[i0], m0 = ai[i0];
                const float r1 = ar[i1], m1 = ai[i1];
                ar[i0] = U00r*r0 - U00i*m0 + U01r*r1 - U01i*m1;
                ai[i0] = U00r*m0 + U00i*r0 + U01r*m1 + U01i*r1;
                ar[i1] = U10r*r0 - U10i*m0 + U11r*r1 - U11i*m1;
                ai[i1] = U10r*m0 + U10i*r0 + U11r*m1 + U11i*r1;
            }
        }
        #pragma unroll
        for (int q = 0; q < 3; ++q) {
            const int cbit = 1 << (3 - q), tbit = 1 << (2 - q);
            #pragma unroll
            for (int idx = 0; idx < 16; ++idx) {
                if ((idx & cbit) && !(idx & tbit)) {
                    const int j = idx | tbit;
                    float tr = ar[idx]; ar[idx] = ar[j]; ar[j] = tr;
                    float ti = ai[idx]; ai[idx] = ai[j]; ai[j] = ti;
                }
            }
        }
    }
    float qo[4];
    #pragma unroll
    for (int q = 0; q < 4; ++q) {
        const int pb = 1 << (3 - q);
        float s = 0.f;
        #pragma unroll
        for (int idx = 0; idx < 16; ++idx) {
            const float pv = ar[idx]*ar[idx] + ai[idx]*ai[idx];
            s += (idx & pb) ? -pv : pv;
        }
        qo[q] = s;
    }
    float z[10];
    float mx = -1e30f;
    #pragma unroll
    for (int o = 0; o < 10; ++o) {
        float a = fc4b[o];
        #pragma unroll
        for (int j = 0; j < 16; ++j) a = fmaf(feat[j], fc4w[o*20 + j], a);
        #pragma unroll
        for (int j = 0; j < 4;  ++j) a = fmaf(qo[j],  fc4w[o*20 + 16 + j], a);
        z[o] = a; mx = fmaxf(mx, a);
    }
    float se = 0.f;
    #pragma unroll
    for (int o = 0; o < 10; ++o) se += expf(z[o] - mx);
    const float lse = logf(se);
    #pragma unroll
    for (int o = 0; o < 10; ++o) outp[o] = z[o] - mx - lse;
}

// ---------------------------------------------------------------------------
// Fallback monolith (round 11 verbatim, linear layouts): bf16 fc1w from ws.
// Used only if ws_size < 7.75 MB (never observed; ws is ~268 MB).
// ---------------------------------------------------------------------------
__global__ __launch_bounds__(256) void k_fused_b(
    const float* __restrict__ x,
    const float* __restrict__ c1w, const float* __restrict__ c1b,
    const float* __restrict__ c2w, const float* __restrict__ c2b,
    const ushort_t* __restrict__ fc1wb, const float* __restrict__ fc1b,
    const float* __restrict__ fc2w, const float* __restrict__ fc2b,
    const float* __restrict__ fc3w, const float* __restrict__ fc3b,
    const float* __restrict__ qw,
    const float* __restrict__ fc4w, const float* __restrict__ fc4b,
    float* __restrict__ out)
{
    __shared__ __align__(16) ushort_t p1cl[8192];
    __shared__ __align__(16) float p2[3136];
    __shared__ float h1s[128];
    __shared__ float h2s[64];
    __shared__ float fts[16];

    const int b = blockIdx.x, t = threadIdx.x;
    const int lane = t & 63, wv = t >> 6;

    for (int i = t; i < 4096; i += 256) ((uint_t*)p1cl)[i] = 0u;
    float* img = p2;
    for (int i = t; i < 900; i += 256) img[i] = 0.f;
    __syncthreads();
    const float* xi = x + (size_t)b * 784;
    for (int i = t; i < 784; i += 256)
        img[(i/28 + 1)*30 + (i%28 + 1)] = xi[i];
    __syncthreads();

    {
        const int ocb1 = wv*8;
        float wk[8][9], bv[8];
        #pragma unroll
        for (int o = 0; o < 8; ++o) {
            bv[o] = c1b[ocb1 + o];
            #pragma unroll
            for (int k = 0; k < 9; ++k) wk[o][k] = c1w[(ocb1 + o)*9 + k];
        }
        #pragma unroll
        for (int ch = 0; ch < 4; ++ch) {
            int pos = ch*64 + lane;
            const bool act = pos < 196;
            if (!act) pos = 195;
            const int qy = pos / 14, qx = pos % 14;
            const float* ib = img + (2*qy)*30 + 2*qx;
            float v[4][4];
            #pragma unroll
            for (int rr = 0; rr < 4; ++rr) {
                const float2 a = *(const float2*)(ib + rr*30);
                const float2 c = *(const float2*)(ib + rr*30 + 2);
                v[rr][0]=a.x; v[rr][1]=a.y; v[rr][2]=c.x; v[rr][3]=c.y;
            }
            short8v pk;
            #pragma unroll
            for (int o = 0; o < 8; ++o) {
                float m = 0.f;
                #pragma unroll
                for (int dy = 0; dy < 2; ++dy)
                #pragma unroll
                for (int dx = 0; dx < 2; ++dx) {
                    float acc = bv[o];
                    #pragma unroll
                    for (int ky = 0; ky < 3; ++ky)
                    #pragma unroll
                    for (int kx = 0; kx < 3; ++kx)
                        acc = fmaf(v[dy+ky][dx+kx], wk[o][ky*3+kx], acc);
                    m = fmaxf(m, acc);
                }
                pk[o] = (short)f2bf(m);
            }
            if (act) *(short8v*)&p1cl[wv*2048 + ((qy+1)*16 + (qx+1))*8] = pk;
        }
    }
    __syncthreads();

    {
        const int ocb = wv*16;
        const int col = lane & 15, g = lane >> 4;
        const int oc  = ocb + col;
        short8v bfr[9];
        #pragma unroll
        for (int j = 0; j < 8; ++j) {
            const float* wp = c2w + ((size_t)oc*32 + g*8 + j)*9;
            #pragma unroll
            for (int s = 0; s < 9; ++s) bfr[s][j] = (short)f2bf(wp[s]);
        }
        const float bv = c2b[oc];
        #pragma unroll 1
        for (int mt = 0; mt < 13; ++mt) {
            int row = mt*16 + col; if (row > 195) row = 195;
            const int q  = row >> 2;
            const int py = q / 7, px = q - py*7;
            const int y0 = 2*py + ((row>>1)&1), x0 = 2*px + (row&1);
            const ushort_t* ap = &p1cl[g*2048 + (y0*16 + x0)*8];
            float4v c0 = {bv, bv, bv, bv};
            float4v c1 = {0.f, 0.f, 0.f, 0.f};
            c0 = __builtin_amdgcn_mfma_f32_16x16x32_bf16(*(const short8v*)(ap +   0), bfr[0], c0, 0, 0, 0);
            c1 = __builtin_amdgcn_mfma_f32_16x16x32_bf16(*(const short8v*)(ap +   8), bfr[1], c1, 0, 0, 0);
            c0 = __builtin_amdgcn_mfma_f32_16x16x32_bf16(*(const short8v*)(ap +  16), bfr[2], c0, 0, 0, 0);
            c1 = __builtin_amdgcn_mfma_f32_16x16x32_bf16(*(const short8v*)(ap + 128), bfr[3], c1, 0, 0, 0);
            c0 = __builtin_amdgcn_mfma_f32_16x16x32_bf16(*(const short8v*)(ap + 136), bfr[4], c0, 0, 0, 0);
            c1 = __builtin_amdgcn_mfma_f32_16x16x32_bf16(*(const short8v*)(ap + 144), bfr[5], c1, 0, 0, 0);
            c0 = __builtin_amdgcn_mfma_f32_16x16x32_bf16(*(const short8v*)(ap + 256), bfr[6], c0, 0, 0, 0);
            c1 = __builtin_amdgcn_mfma_f32_16x16x32_bf16(*(const short8v*)(ap + 264), bfr[7], c1, 0, 0, 0);
            c0 = __builtin_amdgcn_mfma_f32_16x16x32_bf16(*(const short8v*)(ap + 272), bfr[8], c0, 0, 0, 0);
            const int quad = mt*4 + g;
            if (quad < 49) {
                const float m0 = fmaxf(fmaxf(c0[0]+c1[0], c0[1]+c1[1]),
                                       fmaxf(c0[2]+c1[2], c0[3]+c1[3]));
                p2[oc*49 + quad] = fmaxf(m0, 0.f);
            }
        }
    }
    __syncthreads();

    for (int pass = 0; pass < 8; ++pass) {
        const int o = wv*32 + pass*4;
        const ushort_t* w0 = fc1wb + (size_t)o*3136;
        float a0=0.f, a1=0.f, a2=0.f, a3=0.f;
        #pragma unroll 2
        for (int kb = 0; kb < 3072; kb += 256) {
            const int k = kb + lane*4;
            const float4 pv = *(const float4*)&p2[k];
            const ushort4v u0 = *(const ushort4v*)(w0 + k);
            const ushort4v u1 = *(const ushort4v*)(w0 + 3136 + k);
            const ushort4v u2 = *(const ushort4v*)(w0 + 6272 + k);
            const ushort4v u3 = *(const ushort4v*)(w0 + 9408 + k);
            a0 = fmaf(pv.x,bf2f(u0[0]),fmaf(pv.y,bf2f(u0[1]),fmaf(pv.z,bf2f(u0[2]),fmaf(pv.w,bf2f(u0[3]),a0))));
            a1 = fmaf(pv.x,bf2f(u1[0]),fmaf(pv.y,bf2f(u1[1]),fmaf(pv.z,bf2f(u1[2]),fmaf(pv.w,bf2f(u1[3]),a1))));
            a2 = fmaf(pv.x,bf2f(u2[0]),fmaf(pv.y,bf2f(u2[1]),fmaf(pv.z,bf2f(u2[2]),fmaf(pv.w,bf2f(u2[3]),a2))));
            a3 = fmaf(pv.x,bf2f(u3[0]),fmaf(pv.y,bf2f(u3[1]),fmaf(pv.z,bf2f(u3[2]),fmaf(pv.w,bf2f(u3[3]),a3))));
        }
        if (lane < 16) {
            const int k = 3072 + lane*4;
            const float4 pv = *(const float4*)&p2[k];
            const ushort4v u0 = *(const ushort4v*)(w0 + k);
            const ushort4v u1 = *(const ushort4v*)(w0 + 3136 + k);
            const ushort4v u2 = *(const ushort4v*)(w0 + 6272 + k);
            const ushort4v u3 = *(const ushort4v*)(w0 + 9408 + k);
            a0 = fmaf(pv.x,bf2f(u0[0]),fmaf(pv.y,bf2f(u0[1]),fmaf(pv.z,bf2f(u0[2]),fmaf(pv.w,bf2f(u0[3]),a0))));
            a1 = fmaf(pv.x,bf2f(u1[0]),fmaf(pv.y,bf2f(u1[1]),fmaf(pv.z,bf2f(u1[2]),fmaf(pv.w,bf2f(u1[3]),a1))));
            a2 = fmaf(pv.x,bf2f(u2[0]),fmaf(pv.y,bf2f(u2[1]),fmaf(pv.z,bf2f(u2[2]),fmaf(pv.w,bf2f(u2[3]),a2))));
            a3 = fmaf(pv.x,bf2f(u3[0]),fmaf(pv.y,bf2f(u3[1]),fmaf(pv.z,bf2f(u3[2]),fmaf(pv.w,bf2f(u3[3]),a3))));
        }
        #pragma unroll
        for (int s = 1; s < 64; s <<= 1) {
            a0 += __shfl_xor(a0, s);
            a1 += __shfl_xor(a1, s);
            a2 += __shfl_xor(a2, s);
            a3 += __shfl_xor(a3, s);
        }
        if (lane == ((o+0)&63)) h1s[o+0] = fmaxf(a0 + fc1b[o+0], 0.f);
        if (lane == ((o+1)&63)) h1s[o+1] = fmaxf(a1 + fc1b[o+1], 0.f);
        if (lane == ((o+2)&63)) h1s[o+2] = fmaxf(a2 + fc1b[o+2], 0.f);
        if (lane == ((o+3)&63)) h1s[o+3] = fmaxf(a3 + fc1b[o+3], 0.f);
    }
    __syncthreads();

    if (t < 64) {
        float a = fc2b[t];
        const float* wr = fc2w + t * 128;
        for (int k = 0; k < 128; ++k) a = fmaf(h1s[k], wr[k], a);
        h2s[t] = fmaxf(a, 0.f);
    }
    __syncthreads();
    if (t < 16) {
        float a = fc3b[t];
        const float* wr = fc3w + t * 64;
        for (int k = 0; k < 64; ++k) a = fmaf(h2s[k], wr[k], a);
        fts[t] = fmaxf(a, 0.f);
    }
    __syncthreads();
    if (t == 0) circuit_head(fts, qw, fc4w, fc4b, out + (size_t)b*10);
}

__global__ __launch_bounds__(256) void k_cvtw_fb(
    const float* __restrict__ w, ushort_t* __restrict__ o)
{
    const int i = (blockIdx.x*256 + threadIdx.x) * 8;
    const float4 a = *(const float4*)(w + i);
    const float4 b = *(const float4*)(w + i + 4);
    short8v pk;
    pk[0]=(short)f2bf(a.x); pk[1]=(short)f2bf(a.y);
    pk[2]=(short)f2bf(a.z); pk[3]=(short)f2bf(a.w);
    pk[4]=(short)f2bf(b.x); pk[5]=(short)f2bf(b.y);
    pk[6]=(short)f2bf(b.z); pk[7]=(short)f2bf(b.w);
    *(short8v*)(o + i) = pk;
}

// ---------------------------------------------------------------------------
extern "C" void kernel_launch(void* const* d_in, const int* in_sizes, int n_in,
                              void* d_out, int out_size, void* d_ws, size_t ws_size,
                              hipStream_t stream) {
    const float* x     = (const float*)d_in[0];
    const float* c1w   = (const float*)d_in[1];
    const float* c1b   = (const float*)d_in[2];
    const float* c2w   = (const float*)d_in[3];
    const float* c2b   = (const float*)d_in[4];
    const float* fc1w  = (const float*)d_in[5];
    const float* fc1b  = (const float*)d_in[6];
    const float* fc2w  = (const float*)d_in[7];
    const float* fc2b  = (const float*)d_in[8];
    const float* fc3w  = (const float*)d_in[9];
    const float* fc3b  = (const float*)d_in[10];
    const float* qwp   = (const float*)d_in[11];
    const float* fc4w  = (const float*)d_in[12];
    const float* fc4b  = (const float*)d_in[13];
    float* outp = (float*)d_out;

    const size_t WB  = (size_t)128*3136*2;     // 802816  fc1w bf16
    const size_t P2B = (size_t)1024*3136*2;    // 6422528 p2 bf16
    const size_t H1B = (size_t)1024*128*4;     // 524288  h1 fp32

    if (ws_size >= WB + P2B + H1B) {
        ushort_t* wb  = (ushort_t*)d_ws;
        ushort_t* p2g = (ushort_t*)((char*)d_ws + WB);
        float*    h1g = (float*)((char*)d_ws + WB + P2B);
        k_conv<<<1220, 256, 0, stream>>>(x, c1w, c1b, c2w, c2b, fc1w, wb, p2g);
        k_fc1<<<dim3(64, 8), 256, 0, stream>>>(p2g, wb, fc1b, h1g);
        k_head<<<256, 64, 0, stream>>>(h1g, fc2w, fc2b, fc3w, fc3b, qwp,
                                       fc4w, fc4b, outp);
    } else if (ws_size >= WB) {
        ushort_t* wb = (ushort_t*)d_ws;
        k_cvtw_fb<<<196, 256, 0, stream>>>(fc1w, wb);
        k_fused_b<<<1024, 256, 0, stream>>>(x, c1w, c1b, c2w, c2b, wb, fc1b,
                                            fc2w, fc2b, fc3w, fc3b, qwp,
                                            fc4w, fc4b, outp);
    }
}

// Round 19
// 56.886 us; speedup vs baseline: 1.0157x; 1.0157x over previous
//
#include <hip/hip_runtime.h>
#include <math.h>

typedef unsigned short ushort_t;
typedef unsigned int uint_t;
typedef __attribute__((ext_vector_type(8))) short short8v;       // 8 bf16 = 4 VGPR
typedef __attribute__((ext_vector_type(4))) float float4v;       // MFMA accum
typedef __attribute__((ext_vector_type(4))) unsigned short ushort4v; // 8B load

static __device__ __forceinline__ ushort_t f2bf(float f) {
    union { float f; uint_t u; } v; v.f = f;
    uint_t r = (v.u + 0x7FFFu + ((v.u >> 16) & 1u)) >> 16;       // RNE
    return (ushort_t)r;
}
static __device__ __forceinline__ float bf2f(ushort_t u) {
    union { uint_t u; float f; } v; v.u = ((uint_t)u) << 16;
    return v.f;
}

// ---------------------------------------------------------------------------
// K1 (round-14 proven): blocks 0..1023: conv1+pool -> conv2+pool (MFMA) ->
// p2g bf16. Blocks 1024..1219: convert fc1w fp32 -> bf16 into wb.
// ---------------------------------------------------------------------------
__global__ __launch_bounds__(256) void k_conv(
    const float* __restrict__ x,
    const float* __restrict__ c1w, const float* __restrict__ c1b,
    const float* __restrict__ c2w, const float* __restrict__ c2b,
    const float* __restrict__ fc1w, ushort_t* __restrict__ wb,
    ushort_t* __restrict__ p2g)
{
    const int t = threadIdx.x;
    if (blockIdx.x >= 1024) {                                 // fused cvtw
        const int i = ((blockIdx.x - 1024)*256 + t) * 8;
        const float4 a = *(const float4*)(fc1w + i);
        const float4 b = *(const float4*)(fc1w + i + 4);
        short8v pk;
        pk[0]=(short)f2bf(a.x); pk[1]=(short)f2bf(a.y);
        pk[2]=(short)f2bf(a.z); pk[3]=(short)f2bf(a.w);
        pk[4]=(short)f2bf(b.x); pk[5]=(short)f2bf(b.y);
        pk[6]=(short)f2bf(b.z); pk[7]=(short)f2bf(b.w);
        *(short8v*)(wb + i) = pk;
        return;
    }

    __shared__ __align__(16) ushort_t p1cl[8192];            // 16 KB, 4 ic-planes
    __shared__ __align__(16) float img[900];                 // 30x30 padded

    const int b = blockIdx.x;
    const int lane = t & 63, wv = t >> 6;

    for (int i = t; i < 4096; i += 256) ((uint_t*)p1cl)[i] = 0u;
    for (int i = t; i < 900; i += 256) img[i] = 0.f;
    __syncthreads();
    const float* xi = x + (size_t)b * 784;
    for (int i = t; i < 784; i += 256)
        img[(i/28 + 1)*30 + (i%28 + 1)] = xi[i];
    __syncthreads();

    // ---- conv1 (1->32) + ReLU + maxpool2 -> p1cl (bf16, plane = wv) ----
    {
        const int ocb1 = wv*8;
        float wk[8][9], bv[8];
        #pragma unroll
        for (int o = 0; o < 8; ++o) {
            bv[o] = c1b[ocb1 + o];
            #pragma unroll
            for (int k = 0; k < 9; ++k) wk[o][k] = c1w[(ocb1 + o)*9 + k];
        }
        #pragma unroll
        for (int ch = 0; ch < 4; ++ch) {
            int pos = ch*64 + lane;
            const bool act = pos < 196;
            if (!act) pos = 195;
            const int qy = pos / 14, qx = pos % 14;
            const float* ib = img + (2*qy)*30 + 2*qx;
            float v[4][4];
            #pragma unroll
            for (int rr = 0; rr < 4; ++rr) {
                const float2 a = *(const float2*)(ib + rr*30);
                const float2 c = *(const float2*)(ib + rr*30 + 2);
                v[rr][0]=a.x; v[rr][1]=a.y; v[rr][2]=c.x; v[rr][3]=c.y;
            }
            short8v pk;
            #pragma unroll
            for (int o = 0; o < 8; ++o) {
                float m = 0.f;                                // relu(max)==max(0,max)
                #pragma unroll
                for (int dy = 0; dy < 2; ++dy)
                #pragma unroll
                for (int dx = 0; dx < 2; ++dx) {
                    float acc = bv[o];
                    #pragma unroll
                    for (int ky = 0; ky < 3; ++ky)
                    #pragma unroll
                    for (int kx = 0; kx < 3; ++kx)
                        acc = fmaf(v[dy+ky][dx+kx], wk[o][ky*3+kx], acc);
                    m = fmaxf(m, acc);
                }
                pk[o] = (short)f2bf(m);
            }
            if (act) *(short8v*)&p1cl[wv*2048 + ((qy+1)*16 + (qx+1))*8] = pk;
        }
    }
    __syncthreads();

    // ---- conv2 (32->64) + ReLU + maxpool2 via MFMA -> p2g (bf16) ----
    {
        const int ocb = wv*16;
        const int col = lane & 15, g = lane >> 4;
        const int oc  = ocb + col;
        short8v bfr[9];
        #pragma unroll
        for (int j = 0; j < 8; ++j) {
            const float* wp = c2w + ((size_t)oc*32 + g*8 + j)*9;
            #pragma unroll
            for (int s = 0; s < 9; ++s) bfr[s][j] = (short)f2bf(wp[s]);
        }
        const float bv = c2b[oc];
        ushort_t* po = p2g + (size_t)b*3136;
        #pragma unroll 1
        for (int mt = 0; mt < 13; ++mt) {
            int row = mt*16 + col; if (row > 195) row = 195;
            const int q  = row >> 2;
            const int py = q / 7, px = q - py*7;
            const int y0 = 2*py + ((row>>1)&1), x0 = 2*px + (row&1);
            const ushort_t* ap = &p1cl[g*2048 + (y0*16 + x0)*8];
            float4v c0 = {bv, bv, bv, bv};
            float4v c1 = {0.f, 0.f, 0.f, 0.f};
            c0 = __builtin_amdgcn_mfma_f32_16x16x32_bf16(*(const short8v*)(ap +   0), bfr[0], c0, 0, 0, 0);
            c1 = __builtin_amdgcn_mfma_f32_16x16x32_bf16(*(const short8v*)(ap +   8), bfr[1], c1, 0, 0, 0);
            c0 = __builtin_amdgcn_mfma_f32_16x16x32_bf16(*(const short8v*)(ap +  16), bfr[2], c0, 0, 0, 0);
            c1 = __builtin_amdgcn_mfma_f32_16x16x32_bf16(*(const short8v*)(ap + 128), bfr[3], c1, 0, 0, 0);
            c0 = __builtin_amdgcn_mfma_f32_16x16x32_bf16(*(const short8v*)(ap + 136), bfr[4], c0, 0, 0, 0);
            c1 = __builtin_amdgcn_mfma_f32_16x16x32_bf16(*(const short8v*)(ap + 144), bfr[5], c1, 0, 0, 0);
            c0 = __builtin_amdgcn_mfma_f32_16x16x32_bf16(*(const short8v*)(ap + 256), bfr[6], c0, 0, 0, 0);
            c1 = __builtin_amdgcn_mfma_f32_16x16x32_bf16(*(const short8v*)(ap + 264), bfr[7], c1, 0, 0, 0);
            c0 = __builtin_amdgcn_mfma_f32_16x16x32_bf16(*(const short8v*)(ap + 272), bfr[8], c0, 0, 0, 0);
            const int quad = mt*4 + g;
            if (quad < 49) {
                const float m0 = fmaxf(fmaxf(c0[0]+c1[0], c0[1]+c1[1]),
                                       fmaxf(c0[2]+c1[2], c0[3]+c1[3]));
                po[oc*49 + quad] = f2bf(fmaxf(m0, 0.f));
            }
        }
    }
}

// ---------------------------------------------------------------------------
// K2: fc1 as bf16 MFMA GEMM. C[img16][oc16] per block; grid (64 imgT, 8 ocT).
// K = 98 chunks of 32 split 25/25/24/24 across 4 waves; 2-stage pipelined.
// ---------------------------------------------------------------------------
__global__ __launch_bounds__(256) void k_fc1(
    const ushort_t* __restrict__ p2g, const ushort_t* __restrict__ wb,
    const float* __restrict__ fc1b, float* __restrict__ h1g)
{
    __shared__ float cred[4][16][16];
    const int t = threadIdx.x, lane = t & 63, wv = t >> 6;
    const int imgT = blockIdx.x, ocT = blockIdx.y;
    const int sel = lane & 15, koff = (lane >> 4) * 8;
    const ushort_t* arow = p2g + (size_t)(imgT*16 + sel)*3136;
    const ushort_t* brow = wb  + (size_t)(ocT*16 + sel)*3136;
    const int n    = (wv < 2) ? 25 : 24;                      // 25+25+24+24 = 98
    const int kbeg = wv*24 + (wv < 2 ? wv : 2);
    float4v c = {0.f, 0.f, 0.f, 0.f};
    int k0 = kbeg*32 + koff;
    short8v a0 = *(const short8v*)(arow + k0);
    short8v b0 = *(const short8v*)(brow + k0);
    for (int kk = 1; kk < n; ++kk) {
        const int k1 = (kbeg + kk)*32 + koff;
        const short8v a1 = *(const short8v*)(arow + k1);
        const short8v b1 = *(const short8v*)(brow + k1);
        c = __builtin_amdgcn_mfma_f32_16x16x32_bf16(a0, b0, c, 0, 0, 0);
        a0 = a1; b0 = b1;
    }
    c = __builtin_amdgcn_mfma_f32_16x16x32_bf16(a0, b0, c, 0, 0, 0);
    #pragma unroll
    for (int r = 0; r < 4; ++r) cred[wv][(lane>>4)*4 + r][sel] = c[r];
    __syncthreads();
    const int m = t >> 4, nn = t & 15;
    const float s = cred[0][m][nn] + cred[1][m][nn] + cred[2][m][nn] + cred[3][m][nn]
                  + fc1b[ocT*16 + nn];
    h1g[(size_t)(imgT*16 + m)*128 + ocT*16 + nn] = fmaxf(s, 0.f);
}

// ---------------------------------------------------------------------------
// K3: tail (verified). 64-thread blocks, 4 samples each, grid 256.
// fc2+ReLU, fc3+ReLU, 4-qubit circuit via shfl, fc4, log_softmax.
// ---------------------------------------------------------------------------
__global__ __launch_bounds__(64) void k_head(
    const float* __restrict__ h1,
    const float* __restrict__ fc2w, const float* __restrict__ fc2b,
    const float* __restrict__ fc3w, const float* __restrict__ fc3b,
    const float* __restrict__ qw,
    const float* __restrict__ fc4w, const float* __restrict__ fc4b,
    float* __restrict__ out)
{
    __shared__ float h1s[4][132];
    __shared__ float h2s[4][68];
    __shared__ float fs[4][16];
    __shared__ float zs[4][12];
    const int t = threadIdx.x;                   // 0..63, one wave
    const int r = t >> 4, l = t & 15;            // sample-in-block, lane-in-sample
    const int b0 = blockIdx.x * 4;
    for (int i = t; i < 4*128; i += 64) h1s[i>>7][i&127] = h1[(size_t)b0*128 + i];
    __syncthreads();

    // fc2: each thread computes outputs o0..o0+3 of its sample
    const int o0 = l*4;
    float a0 = fc2b[o0+0], a1 = fc2b[o0+1], a2 = fc2b[o0+2], a3 = fc2b[o0+3];
    #pragma unroll 4
    for (int k4 = 0; k4 < 32; ++k4) {
        const float4 h  = *(const float4*)&h1s[r][k4*4];
        const float4 w0 = *(const float4*)&fc2w[(o0+0)*128 + k4*4];
        const float4 w1 = *(const float4*)&fc2w[(o0+1)*128 + k4*4];
        const float4 w2 = *(const float4*)&fc2w[(o0+2)*128 + k4*4];
        const float4 w3 = *(const float4*)&fc2w[(o0+3)*128 + k4*4];
        a0 = fmaf(h.x,w0.x,fmaf(h.y,w0.y,fmaf(h.z,w0.z,fmaf(h.w,w0.w,a0))));
        a1 = fmaf(h.x,w1.x,fmaf(h.y,w1.y,fmaf(h.z,w1.z,fmaf(h.w,w1.w,a1))));
        a2 = fmaf(h.x,w2.x,fmaf(h.y,w2.y,fmaf(h.z,w2.z,fmaf(h.w,w2.w,a2))));
        a3 = fmaf(h.x,w3.x,fmaf(h.y,w3.y,fmaf(h.z,w3.z,fmaf(h.w,w3.w,a3))));
    }
    {
        float4 v = make_float4(fmaxf(a0,0.f), fmaxf(a1,0.f), fmaxf(a2,0.f), fmaxf(a3,0.f));
        *(float4*)&h2s[r][o0] = v;
    }
    __syncthreads();

    // fc3: thread computes feat[l]
    float facc = fc3b[l];
    #pragma unroll 4
    for (int k4 = 0; k4 < 16; ++k4) {
        const float4 h  = *(const float4*)&h2s[r][k4*4];
        const float4 wv = *(const float4*)&fc3w[l*64 + k4*4];
        facc = fmaf(h.x,wv.x,fmaf(h.y,wv.y,fmaf(h.z,wv.z,fmaf(h.w,wv.w,facc))));
    }
    const float feat = fmaxf(facc, 0.f);
    fs[r][l] = feat;

    // ---- quantum circuit: amplitude per lane (bit of qubit q is 3-q) ----
    float nrm2 = feat*feat;
    nrm2 += __shfl_xor(nrm2, 1);
    nrm2 += __shfl_xor(nrm2, 2);
    nrm2 += __shfl_xor(nrm2, 4);
    nrm2 += __shfl_xor(nrm2, 8);
    const float nrm = fmaxf(sqrtf(nrm2), 1e-12f);
    float re = feat / nrm, im = 0.f;
    #pragma unroll
    for (int layer = 0; layer < 2; ++layer) {
        #pragma unroll
        for (int q = 0; q < 4; ++q) {
            const float phi = qw[(layer*4 + q)*3 + 0];
            const float th  = qw[(layer*4 + q)*3 + 1];
            const float om  = qw[(layer*4 + q)*3 + 2];
            float st, ct; sincosf(0.5f*th, &st, &ct);
            float sa, ca; sincosf(0.5f*(phi + om), &sa, &ca);   // ep = ca - i sa
            float sb, cb; sincosf(0.5f*(phi - om), &sb, &cb);   // em = cb + i sb
            const int pbit = 3 - q;
            const int bit  = (l >> pbit) & 1;
            const float pre = __shfl_xor(re, 1 << pbit);
            const float pim = __shfl_xor(im, 1 << pbit);
            const float sel = bit ? 1.f : -1.f;
            const float coR = ca*ct;
            const float coI = sel*sa*ct;
            const float cpR = sel*cb*st;
            const float cpI = -sb*st;
            const float nr = coR*re - coI*im + cpR*pre - cpI*pim;
            const float ni = coR*im + coI*re + cpR*pim + cpI*pre;
            re = nr; im = ni;
        }
        #pragma unroll
        for (int q = 0; q < 3; ++q) {          // CNOT control=q, target=q+1
            const int cbit = 3 - q, tbit = 2 - q;
            const float sre = __shfl_xor(re, 1 << tbit);
            const float sim = __shfl_xor(im, 1 << tbit);
            if ((l >> cbit) & 1) { re = sre; im = sim; }
        }
    }
    const float pr = fmaf(re, re, im*im);
    float qo[4];
    #pragma unroll
    for (int q = 0; q < 4; ++q) {
        float v = ((l >> (3-q)) & 1) ? -pr : pr;
        v += __shfl_xor(v, 1);
        v += __shfl_xor(v, 2);
        v += __shfl_xor(v, 4);
        v += __shfl_xor(v, 8);
        qo[q] = v;
    }
    __syncthreads();

    // fc4 + log_softmax (10 lanes per sample active)
    if (l < 10) {
        float z = fc4b[l];
        #pragma unroll
        for (int j = 0; j < 16; ++j) z = fmaf(fs[r][j], fc4w[l*20 + j], z);
        #pragma unroll
        for (int j = 0; j < 4; ++j)  z = fmaf(qo[j], fc4w[l*20 + 16 + j], z);
        zs[r][l] = z;
        float mx = zs[r][0];
        #pragma unroll
        for (int j = 1; j < 10; ++j) mx = fmaxf(mx, zs[r][j]);
        float se = 0.f;
        #pragma unroll
        for (int j = 0; j < 10; ++j) se += expf(zs[r][j] - mx);
        out[(size_t)(b0 + r)*10 + l] = z - mx - logf(se);
    }
}

// ---------------------------------------------------------------------------
// Serial per-sample head (verified round 3+), used by fallback monolith.
// ---------------------------------------------------------------------------
static __device__ __forceinline__ void circuit_head(
    const float* feat_in, const float* __restrict__ qw,
    const float* __restrict__ fc4w, const float* __restrict__ fc4b,
    float* __restrict__ outp)
{
    float feat[16];
    #pragma unroll
    for (int j = 0; j < 16; ++j) feat[j] = feat_in[j];
    float nrm2 = 0.f;
    #pragma unroll
    for (int j = 0; j < 16; ++j) nrm2 += feat[j]*feat[j];
    const float inv = 1.f / fmaxf(sqrtf(nrm2), 1e-12f);
    float ar[16], ai[16];
    #pragma unroll
    for (int j = 0; j < 16; ++j) { ar[j] = feat[j]*inv; ai[j] = 0.f; }
    #pragma unroll
    for (int layer = 0; layer < 2; ++layer) {
        #pragma unroll
        for (int q = 0; q < 4; ++q) {
            const float phi = qw[(layer*4 + q)*3 + 0];
            const float th  = qw[(layer*4 + q)*3 + 1];
            const float om  = qw[(layer*4 + q)*3 + 2];
            float st, ct; sincosf(0.5f*th, &st, &ct);
            float sa, ca; sincosf(0.5f*(phi + om), &sa, &ca);
            float sb, cb; sincosf(0.5f*(phi - om), &sb, &cb);
            const float U00r =  ca*ct, U00i = -sa*ct;
            const float U01r = -cb*st, U01i = -sb*st;
            const float U10r =  cb*st, U10i = -sb*st;
            const float U11r =  ca*ct, U11i =  sa*ct;
            const int stride = 1 << (3 - q);
            #pragma unroll
            for (int i0 = 0; i0 < 16; ++i0) {
                if (i0 & stride) continue;
                const int i1 = i0 | stride;
                const float r0 = ar[i0], m0 = ai[i0];
                const float r1 = ar[i1], m1 = ai[i1];
                ar[i0] = U00r*r0 - U00i*m0 + U01r*r1 - U01i*m1;
                ai[i0] = U00r*m0 + U00i*r0 + U01r*m1 + U01i*r1;
                ar[i1] = U10r*r0 - U10i*m0 + U11r*r1 - U11i*m1;
                ai[i1] = U10r*m0 + U10i*r0 + U11r*m1 + U11i*r1;
            }
        }
        #pragma unroll
        for (int q = 0; q < 3; ++q) {
            const int cbit = 1 << (3 - q), tbit = 1 << (2 - q);
            #pragma unroll
            for (int idx = 0; idx < 16; ++idx) {
                if ((idx & cbit) && !(idx & tbit)) {
                    const int j = idx | tbit;
                    float tr = ar[idx]; ar[idx] = ar[j]; ar[j] = tr;
                    float ti = ai[idx]; ai[idx] = ai[j]; ai[j] = ti;
                }
            }
        }
    }
    float qo[4];
    #pragma unroll
    for (int q = 0; q < 4; ++q) {
        const int pb = 1 << (3 - q);
        float s = 0.f;
        #pragma unroll
        for (int idx = 0; idx < 16; ++idx) {
            const float pv = ar[idx]*ar[idx] + ai[idx]*ai[idx];
            s += (idx & pb) ? -pv : pv;
        }
        qo[q] = s;
    }
    float z[10];
    float mx = -1e30f;
    #pragma unroll
    for (int o = 0; o < 10; ++o) {
        float a = fc4b[o];
        #pragma unroll
        for (int j = 0; j < 16; ++j) a = fmaf(feat[j], fc4w[o*20 + j], a);
        #pragma unroll
        for (int j = 0; j < 4;  ++j) a = fmaf(qo[j],  fc4w[o*20 + 16 + j], a);
        z[o] = a; mx = fmaxf(mx, a);
    }
    float se = 0.f;
    #pragma unroll
    for (int o = 0; o < 10; ++o) se += expf(z[o] - mx);
    const float lse = logf(se);
    #pragma unroll
    for (int o = 0; o < 10; ++o) outp[o] = z[o] - mx - lse;
}

// ---------------------------------------------------------------------------
// Fallback monolith (round 11 verbatim): bf16 fc1 weights from ws.
// Used only if ws_size < 7.75 MB (never observed; ws is ~268 MB).
// ---------------------------------------------------------------------------
__global__ __launch_bounds__(256) void k_fused_b(
    const float* __restrict__ x,
    const float* __restrict__ c1w, const float* __restrict__ c1b,
    const float* __restrict__ c2w, const float* __restrict__ c2b,
    const ushort_t* __restrict__ fc1wb, const float* __restrict__ fc1b,
    const float* __restrict__ fc2w, const float* __restrict__ fc2b,
    const float* __restrict__ fc3w, const float* __restrict__ fc3b,
    const float* __restrict__ qw,
    const float* __restrict__ fc4w, const float* __restrict__ fc4b,
    float* __restrict__ out)
{
    __shared__ __align__(16) ushort_t p1cl[8192];
    __shared__ __align__(16) float p2[3136];
    __shared__ float h1s[128];
    __shared__ float h2s[64];
    __shared__ float fts[16];

    const int b = blockIdx.x, t = threadIdx.x;
    const int lane = t & 63, wv = t >> 6;

    for (int i = t; i < 4096; i += 256) ((uint_t*)p1cl)[i] = 0u;
    float* img = p2;
    for (int i = t; i < 900; i += 256) img[i] = 0.f;
    __syncthreads();
    const float* xi = x + (size_t)b * 784;
    for (int i = t; i < 784; i += 256)
        img[(i/28 + 1)*30 + (i%28 + 1)] = xi[i];
    __syncthreads();

    {
        const int ocb1 = wv*8;
        float wk[8][9], bv[8];
        #pragma unroll
        for (int o = 0; o < 8; ++o) {
            bv[o] = c1b[ocb1 + o];
            #pragma unroll
            for (int k = 0; k < 9; ++k) wk[o][k] = c1w[(ocb1 + o)*9 + k];
        }
        #pragma unroll
        for (int ch = 0; ch < 4; ++ch) {
            int pos = ch*64 + lane;
            const bool act = pos < 196;
            if (!act) pos = 195;
            const int qy = pos / 14, qx = pos % 14;
            const float* ib = img + (2*qy)*30 + 2*qx;
            float v[4][4];
            #pragma unroll
            for (int rr = 0; rr < 4; ++rr) {
                const float2 a = *(const float2*)(ib + rr*30);
                const float2 c = *(const float2*)(ib + rr*30 + 2);
                v[rr][0]=a.x; v[rr][1]=a.y; v[rr][2]=c.x; v[rr][3]=c.y;
            }
            short8v pk;
            #pragma unroll
            for (int o = 0; o < 8; ++o) {
                float m = 0.f;
                #pragma unroll
                for (int dy = 0; dy < 2; ++dy)
                #pragma unroll
                for (int dx = 0; dx < 2; ++dx) {
                    float acc = bv[o];
                    #pragma unroll
                    for (int ky = 0; ky < 3; ++ky)
                    #pragma unroll
                    for (int kx = 0; kx < 3; ++kx)
                        acc = fmaf(v[dy+ky][dx+kx], wk[o][ky*3+kx], acc);
                    m = fmaxf(m, acc);
                }
                pk[o] = (short)f2bf(m);
            }
            if (act) *(short8v*)&p1cl[wv*2048 + ((qy+1)*16 + (qx+1))*8] = pk;
        }
    }
    __syncthreads();

    {
        const int ocb = wv*16;
        const int col = lane & 15, g = lane >> 4;
        const int oc  = ocb + col;
        short8v bfr[9];
        #pragma unroll
        for (int j = 0; j < 8; ++j) {
            const float* wp = c2w + ((size_t)oc*32 + g*8 + j)*9;
            #pragma unroll
            for (int s = 0; s < 9; ++s) bfr[s][j] = (short)f2bf(wp[s]);
        }
        const float bv = c2b[oc];
        #pragma unroll 1
        for (int mt = 0; mt < 13; ++mt) {
            int row = mt*16 + col; if (row > 195) row = 195;
            const int q  = row >> 2;
            const int py = q / 7, px = q - py*7;
            const int y0 = 2*py + ((row>>1)&1), x0 = 2*px + (row&1);
            const ushort_t* ap = &p1cl[g*2048 + (y0*16 + x0)*8];
            float4v c0 = {bv, bv, bv, bv};
            float4v c1 = {0.f, 0.f, 0.f, 0.f};
            c0 = __builtin_amdgcn_mfma_f32_16x16x32_bf16(*(const short8v*)(ap +   0), bfr[0], c0, 0, 0, 0);
            c1 = __builtin_amdgcn_mfma_f32_16x16x32_bf16(*(const short8v*)(ap +   8), bfr[1], c1, 0, 0, 0);
            c0 = __builtin_amdgcn_mfma_f32_16x16x32_bf16(*(const short8v*)(ap +  16), bfr[2], c0, 0, 0, 0);
            c1 = __builtin_amdgcn_mfma_f32_16x16x32_bf16(*(const short8v*)(ap + 128), bfr[3], c1, 0, 0, 0);
            c0 = __builtin_amdgcn_mfma_f32_16x16x32_bf16(*(const short8v*)(ap + 136), bfr[4], c0, 0, 0, 0);
            c1 = __builtin_amdgcn_mfma_f32_16x16x32_bf16(*(const short8v*)(ap + 144), bfr[5], c1, 0, 0, 0);
            c0 = __builtin_amdgcn_mfma_f32_16x16x32_bf16(*(const short8v*)(ap + 256), bfr[6], c0, 0, 0, 0);
            c1 = __builtin_amdgcn_mfma_f32_16x16x32_bf16(*(const short8v*)(ap + 264), bfr[7], c1, 0, 0, 0);
            c0 = __builtin_amdgcn_mfma_f32_16x16x32_bf16(*(const short8v*)(ap + 272), bfr[8], c0, 0, 0, 0);
            const int quad = mt*4 + g;
            if (quad < 49) {
                const float m0 = fmaxf(fmaxf(c0[0]+c1[0], c0[1]+c1[1]),
                                       fmaxf(c0[2]+c1[2], c0[3]+c1[3]));
                p2[oc*49 + quad] = fmaxf(m0, 0.f);
            }
        }
    }
    __syncthreads();

    for (int pass = 0; pass < 8; ++pass) {
        const int o = wv*32 + pass*4;
        const ushort_t* w0 = fc1wb + (size_t)o*3136;
        float a0=0.f, a1=0.f, a2=0.f, a3=0.f;
        #pragma unroll 2
        for (int kb = 0; kb < 3072; kb += 256) {
            const int k = kb + lane*4;
            const float4 pv = *(const float4*)&p2[k];
            const ushort4v u0 = *(const ushort4v*)(w0 + k);
            const ushort4v u1 = *(const ushort4v*)(w0 + 3136 + k);
            const ushort4v u2 = *(const ushort4v*)(w0 + 6272 + k);
            const ushort4v u3 = *(const ushort4v*)(w0 + 9408 + k);
            a0 = fmaf(pv.x,bf2f(u0[0]),fmaf(pv.y,bf2f(u0[1]),fmaf(pv.z,bf2f(u0[2]),fmaf(pv.w,bf2f(u0[3]),a0))));
            a1 = fmaf(pv.x,bf2f(u1[0]),fmaf(pv.y,bf2f(u1[1]),fmaf(pv.z,bf2f(u1[2]),fmaf(pv.w,bf2f(u1[3]),a1))));
            a2 = fmaf(pv.x,bf2f(u2[0]),fmaf(pv.y,bf2f(u2[1]),fmaf(pv.z,bf2f(u2[2]),fmaf(pv.w,bf2f(u2[3]),a2))));
            a3 = fmaf(pv.x,bf2f(u3[0]),fmaf(pv.y,bf2f(u3[1]),fmaf(pv.z,bf2f(u3[2]),fmaf(pv.w,bf2f(u3[3]),a3))));
        }
        if (lane < 16) {
            const int k = 3072 + lane*4;
            const float4 pv = *(const float4*)&p2[k];
            const ushort4v u0 = *(const ushort4v*)(w0 + k);
            const ushort4v u1 = *(const ushort4v*)(w0 + 3136 + k);
            const ushort4v u2 = *(const ushort4v*)(w0 + 6272 + k);
            const ushort4v u3 = *(const ushort4v*)(w0 + 9408 + k);
            a0 = fmaf(pv.x,bf2f(u0[0]),fmaf(pv.y,bf2f(u0[1]),fmaf(pv.z,bf2f(u0[2]),fmaf(pv.w,bf2f(u0[3]),a0))));
            a1 = fmaf(pv.x,bf2f(u1[0]),fmaf(pv.y,bf2f(u1[1]),fmaf(pv.z,bf2f(u1[2]),fmaf(pv.w,bf2f(u1[3]),a1))));
            a2 = fmaf(pv.x,bf2f(u2[0]),fmaf(pv.y,bf2f(u2[1]),fmaf(pv.z,bf2f(u2[2]),fmaf(pv.w,bf2f(u2[3]),a2))));
            a3 = fmaf(pv.x,bf2f(u3[0]),fmaf(pv.y,bf2f(u3[1]),fmaf(pv.z,bf2f(u3[2]),fmaf(pv.w,bf2f(u3[3]),a3))));
        }
        #pragma unroll
        for (int s = 1; s < 64; s <<= 1) {
            a0 += __shfl_xor(a0, s);
            a1 += __shfl_xor(a1, s);
            a2 += __shfl_xor(a2, s);
            a3 += __shfl_xor(a3, s);
        }
        if (lane == ((o+0)&63)) h1s[o+0] = fmaxf(a0 + fc1b[o+0], 0.f);
        if (lane == ((o+1)&63)) h1s[o+1] = fmaxf(a1 + fc1b[o+1], 0.f);
        if (lane == ((o+2)&63)) h1s[o+2] = fmaxf(a2 + fc1b[o+2], 0.f);
        if (lane == ((o+3)&63)) h1s[o+3] = fmaxf(a3 + fc1b[o+3], 0.f);
    }
    __syncthreads();

    if (t < 64) {
        float a = fc2b[t];
        const float* wr = fc2w + t * 128;
        for (int k = 0; k < 128; ++k) a = fmaf(h1s[k], wr[k], a);
        h2s[t] = fmaxf(a, 0.f);
    }
    __syncthreads();
    if (t < 16) {
        float a = fc3b[t];
        const float* wr = fc3w + t * 64;
        for (int k = 0; k < 64; ++k) a = fmaf(h2s[k], wr[k], a);
        fts[t] = fmaxf(a, 0.f);
    }
    __syncthreads();
    if (t == 0) circuit_head(fts, qw, fc4w, fc4b, out + (size_t)b*10);
}

__global__ __launch_bounds__(256) void k_cvtw_fb(
    const float* __restrict__ w, ushort_t* __restrict__ o)
{
    const int i = (blockIdx.x*256 + threadIdx.x) * 8;
    const float4 a = *(const float4*)(w + i);
    const float4 b = *(const float4*)(w + i + 4);
    short8v pk;
    pk[0]=(short)f2bf(a.x); pk[1]=(short)f2bf(a.y);
    pk[2]=(short)f2bf(a.z); pk[3]=(short)f2bf(a.w);
    pk[4]=(short)f2bf(b.x); pk[5]=(short)f2bf(b.y);
    pk[6]=(short)f2bf(b.z); pk[7]=(short)f2bf(b.w);
    *(short8v*)(o + i) = pk;
}

// ---------------------------------------------------------------------------
extern "C" void kernel_launch(void* const* d_in, const int* in_sizes, int n_in,
                              void* d_out, int out_size, void* d_ws, size_t ws_size,
                              hipStream_t stream) {
    const float* x     = (const float*)d_in[0];
    const float* c1w   = (const float*)d_in[1];
    const float* c1b   = (const float*)d_in[2];
    const float* c2w   = (const float*)d_in[3];
    const float* c2b   = (const float*)d_in[4];
    const float* fc1w  = (const float*)d_in[5];
    const float* fc1b  = (const float*)d_in[6];
    const float* fc2w  = (const float*)d_in[7];
    const float* fc2b  = (const float*)d_in[8];
    const float* fc3w  = (const float*)d_in[9];
    const float* fc3b  = (const float*)d_in[10];
    const float* qwp   = (const float*)d_in[11];
    const float* fc4w  = (const float*)d_in[12];
    const float* fc4b  = (const float*)d_in[13];
    float* outp = (float*)d_out;

    const size_t WB  = (size_t)128*3136*2;     // 802816  fc1w bf16
    const size_t P2B = (size_t)1024*3136*2;    // 6422528 p2 bf16
    const size_t H1B = (size_t)1024*128*4;     // 524288  h1 fp32

    if (ws_size >= WB + P2B + H1B) {
        ushort_t* wb  = (ushort_t*)d_ws;
        ushort_t* p2g = (ushort_t*)((char*)d_ws + WB);
        float*    h1g = (float*)((char*)d_ws + WB + P2B);
        k_conv<<<1220, 256, 0, stream>>>(x, c1w, c1b, c2w, c2b, fc1w, wb, p2g);
        k_fc1<<<dim3(64, 8), 256, 0, stream>>>(p2g, wb, fc1b, h1g);
        k_head<<<256, 64, 0, stream>>>(h1g, fc2w, fc2b, fc3w, fc3b, qwp,
                                       fc4w, fc4b, outp);
    } else if (ws_size >= WB) {
        ushort_t* wb = (ushort_t*)d_ws;
        k_cvtw_fb<<<196, 256, 0, stream>>>(fc1w, wb);
        k_fused_b<<<1024, 256, 0, stream>>>(x, c1w, c1b, c2w, c2b, wb, fc1b,
                                            fc2w, fc2b, fc3w, fc3b, qwp,
                                            fc4w, fc4b, outp);
    }
}